// Round 1
// baseline (520.224 us; speedup 1.0000x reference)
//
#include <hip/hip_runtime.h>
#include <hip/hip_bf16.h>
#include <stdint.h>

#define B_SZ 8192
#define D_SZ 512
#define U_SZ 512
#define M_SZ 16
#define K_SZ 64

typedef short bf16x8 __attribute__((ext_vector_type(8)));
typedef float f32x4 __attribute__((ext_vector_type(4)));

__device__ __forceinline__ unsigned short f2bf(float f) {
  union { float f; unsigned u; } v; v.f = f;
  unsigned r = v.u + 0x7fffu + ((v.u >> 16) & 1u);
  return (unsigned short)(r >> 16);
}

// =====================================================================
// prep1: role-split single launch. ALL outputs are fragment-linear bf16.
//  [0,2048):    kernels [M][D][U] f32 -> kbf [m][ut][kt][j][h][lane][8]
//  [2048,2056): key_kernel [D][K]     -> wkbf [kt][j][h][lane][8]
//  [2056,2568): x [B][D]              -> xbf [bt][kt][i][h][lane][8]
// lane = quad*16+lane16; elem e = k offset kt*64 + h*32 + quad*8 + e.
// =====================================================================
__global__ __launch_bounds__(256) void prep1(
    const float* __restrict__ x, const float* __restrict__ key_kernel,
    const float* __restrict__ kernels, unsigned short* __restrict__ xbf,
    unsigned short* __restrict__ kbf, unsigned short* __restrict__ wkbf) {
  __shared__ float tf[32][65];
  int bid = blockIdx.x;
  int t = threadIdx.x;

  if (bid < 2048) {
    // ---- role T: kernels -> kbf (frag-linear B operand) ----
    int m = bid >> 7;
    int rem = bid & 127;
    int a = (rem >> 3) & 15;  // d-tile (32 d's)
    int ut = rem & 7;         // u-tile (64 u's)
    int d0 = a * 32, u0 = ut * 64;
    {
      int dr = t >> 4, uc = t & 15;
      const float* src = kernels + ((size_t)m * D_SZ + d0 + dr) * U_SZ + u0 + uc * 4;
      float4 aa = *(const float4*)src;
      float4 bb = *(const float4*)(src + (size_t)16 * U_SZ);
      tf[dr][uc * 4 + 0] = aa.x; tf[dr][uc * 4 + 1] = aa.y;
      tf[dr][uc * 4 + 2] = aa.z; tf[dr][uc * 4 + 3] = aa.w;
      tf[dr + 16][uc * 4 + 0] = bb.x; tf[dr + 16][uc * 4 + 1] = bb.y;
      tf[dr + 16][uc * 4 + 2] = bb.z; tf[dr + 16][uc * 4 + 3] = bb.w;
    }
    __syncthreads();
    {
      int ur = t >> 2, dc = t & 3;  // u-row 0..63, d-oct 0..3
      int j = ur >> 4, lane16 = ur & 15;
      int kt = a >> 1, h = a & 1;   // quad == dc (d0 multiple of 32)
      unsigned short* dst = kbf +
          (((((size_t)m * 8 + ut) * 8 + kt) * 4 + j) * 2 + h) * 512 +
          ((size_t)dc * 16 + lane16) * 8;
      ushort4 lo, hi;
      lo.x = f2bf(tf[dc * 8 + 0][ur]); lo.y = f2bf(tf[dc * 8 + 1][ur]);
      lo.z = f2bf(tf[dc * 8 + 2][ur]); lo.w = f2bf(tf[dc * 8 + 3][ur]);
      hi.x = f2bf(tf[dc * 8 + 4][ur]); hi.y = f2bf(tf[dc * 8 + 5][ur]);
      hi.z = f2bf(tf[dc * 8 + 6][ur]); hi.w = f2bf(tf[dc * 8 + 7][ur]);
      *(ushort4*)dst = lo;
      *(ushort4*)(dst + 4) = hi;
    }
    return;
  }

  if (bid < 2056) {
    // ---- role W: key_kernel -> wkbf ----
    int kt = bid - 2048;
#pragma unroll
    for (int rep = 0; rep < 2; ++rep) {
      int c = rep * 256 + t;
      int j = c >> 7, h = (c >> 6) & 1, quad = (c >> 4) & 3, ln = c & 15;
      int dd = kt * 64 + h * 32 + quad * 8;
      int u = j * 16 + ln;
      unsigned short v[8];
#pragma unroll
      for (int e = 0; e < 8; ++e)
        v[e] = f2bf(key_kernel[(size_t)(dd + e) * K_SZ + u]);
      unsigned short* dst =
          wkbf + ((size_t)((kt * 4 + j) * 2 + h) * 64 + quad * 16 + ln) * 8;
#pragma unroll
      for (int e = 0; e < 8; ++e) dst[e] = v[e];
    }
    return;
  }

  // ---- role X: x -> xbf (frag-linear A operand) ----
  int xb0 = bid - 2056;
  int bt = xb0 >> 3, i = xb0 & 7;
  int b0 = xb0 * 16;
#pragma unroll
  for (int rep = 0; rep < 4; ++rep) {
    int idx = rep * 256 + t;
    int kt = idx >> 7, h = (idx >> 6) & 1, quad = (idx >> 4) & 3, ln = idx & 15;
    const float* src = x + (size_t)(b0 + ln) * D_SZ + kt * 64 + h * 32 + quad * 8;
    float4 a = *(const float4*)src;
    float4 b = *(const float4*)(src + 4);
    ushort4 lo, hi;
    lo.x = f2bf(a.x); lo.y = f2bf(a.y); lo.z = f2bf(a.z); lo.w = f2bf(a.w);
    hi.x = f2bf(b.x); hi.y = f2bf(b.y); hi.z = f2bf(b.z); hi.w = f2bf(b.w);
    unsigned short* dst =
        xbf + ((((size_t)bt * 8 + kt) * 8 + i) * 2 + h) * 512 +
        ((size_t)quad * 16 + ln) * 8;
    *(ushort4*)dst = lo;
    *(ushort4*)(dst + 4) = hi;
  }
}

// =====================================================================
// prep2: keyv = xb @ Wk + bias (MFMA, frags direct from global), then sim.
// 128 blocks x 64 rows. No LDS in GEMM loop; one barrier before sim phase.
// =====================================================================
__global__ __launch_bounds__(256) void prep2(
    const unsigned short* __restrict__ xbf, const unsigned short* __restrict__ wkbf,
    const float* __restrict__ key_bias, const float* __restrict__ keys_map,
    float* __restrict__ simT) {
  __shared__ float kv[64][68];
  __shared__ float sKM[16][64];
  int t = threadIdx.x, w = t >> 6, l = t & 63;
  int blk = blockIdx.x;
  int b0 = blk * 64, bt = blk >> 1, ibase = (blk & 1) * 4;
  int lane16 = l & 15, quad = l >> 4;

  ((float4*)sKM)[t] = ((const float4*)keys_map)[t];

  f32x4 acc[4];
#pragma unroll
  for (int j = 0; j < 4; ++j) acc[j] = (f32x4){0.f, 0.f, 0.f, 0.f};

  for (int kt = 0; kt < 8; ++kt) {
    bf16x8 af[2];
#pragma unroll
    for (int h = 0; h < 2; ++h)
      af[h] = *(const bf16x8*)(xbf +
                               ((((size_t)bt * 8 + kt) * 8 + ibase + w) * 2 + h) * 512 +
                               (size_t)l * 8);
#pragma unroll
    for (int j = 0; j < 4; ++j) {
      bf16x8 b0f = *(const bf16x8*)(wkbf + ((size_t)((kt * 4 + j) * 2 + 0) * 64 + l) * 8);
      bf16x8 b1f = *(const bf16x8*)(wkbf + ((size_t)((kt * 4 + j) * 2 + 1) * 64 + l) * 8);
      acc[j] = __builtin_amdgcn_mfma_f32_16x16x32_bf16(af[0], b0f, acc[j], 0, 0, 0);
      acc[j] = __builtin_amdgcn_mfma_f32_16x16x32_bf16(af[1], b1f, acc[j], 0, 0, 0);
    }
  }
#pragma unroll
  for (int j = 0; j < 4; ++j) {
    float bc = key_bias[j * 16 + lane16];
#pragma unroll
    for (int r = 0; r < 4; ++r)
      kv[w * 16 + quad * 4 + r][j * 16 + lane16] = acc[j][r] + bc;
  }
  __syncthreads();

  int row = t >> 2, mg = (t & 3) * 4;
  float d2[4] = {0.f, 0.f, 0.f, 0.f};
#pragma unroll 8
  for (int k = 0; k < 64; ++k) {
    float kvv = kv[row][k];
#pragma unroll
    for (int q = 0; q < 4; ++q) {
      float df = kvv - sKM[mg + q][k];
      d2[q] += df * df;
    }
  }
#pragma unroll
  for (int q = 0; q < 4; ++q)
    simT[(size_t)(mg + q) * B_SZ + b0 + row] = 1.0f / (sqrtf(d2[q]) + 1.0f);
}

// =====================================================================
// poly_gemm: out[b,u] = (1/16) sum_m sim[b,m]*(x@kernels_m + biases_m)
// 512 blocks = 64 bt (128 rows) x 8 ut (64 cols, ut==bid&7 -> XCD-pinned:
// each 1MB kbf mode-slice stays in one XCD's L2).
// NEW: 512 threads = 8 waves = 2 row-halves (rw) x 4 mode-QUARTERS (q).
// 2 blocks/CU x 8 waves = 16 waves/CU = 4 waves/SIMD (was 2) -> latency
// hiding for the global->VGPR fragment loads. Same per-block L2 traffic.
// MAIN LOOP HAS NO LDS AND NO BARRIERS. LDS only for the 4-way epilogue
// mode combine (3 sequential add stages through one 34.8KB buffer).
// =====================================================================
__global__ __launch_bounds__(512, 4) void poly_gemm(
    const unsigned short* __restrict__ xbf,  // A frag-linear
    const unsigned short* __restrict__ kbf,  // B frag-linear
    const float* __restrict__ simT,          // [M][B]
    const float* __restrict__ biases,        // [M][U] f32
    float* __restrict__ out) {               // [B][U]
  __shared__ float sRed[2][64][68];  // 34.8 KB, epilogue only

  int t = threadIdx.x, w = t >> 6, l = t & 63;
  int bid = blockIdx.x;
  int ut = bid & 7, bt = bid >> 3;
  int b0 = bt * 128, u0 = ut * 64;
  int q = w >> 1, rw = w & 1;  // mode quarter, row half
  int lane16 = l & 15, quad = l >> 4;

  f32x4 facc[4][4];
#pragma unroll
  for (int i = 0; i < 4; ++i)
#pragma unroll
    for (int j = 0; j < 4; ++j) facc[i][j] = (f32x4){0.f, 0.f, 0.f, 0.f};

#pragma unroll 1
  for (int kt = 0; kt < 8; ++kt) {
    bf16x8 af[4][2];
#pragma unroll
    for (int ii = 0; ii < 4; ++ii)
#pragma unroll
      for (int h = 0; h < 2; ++h)
        af[ii][h] = *(const bf16x8*)(
            xbf + ((((size_t)bt * 8 + kt) * 8 + rw * 4 + ii) * 2 + h) * 512 +
            (size_t)l * 8);

#pragma unroll 2
    for (int mi = 0; mi < 4; ++mi) {
      int mode = q * 4 + mi;
      const unsigned short* bb =
          kbf + ((((size_t)mode * 8 + ut) * 8 + kt) * 4) * 2 * 512;
      bf16x8 bfr[4][2];
#pragma unroll
      for (int j = 0; j < 4; ++j)
#pragma unroll
        for (int h = 0; h < 2; ++h)
          bfr[j][h] = *(const bf16x8*)(bb + ((size_t)(j * 2 + h)) * 512 +
                                       (size_t)l * 8);

      f32x4 sv[4];
#pragma unroll
      for (int i = 0; i < 4; ++i)
        sv[i] = *(const f32x4*)(simT + (size_t)mode * B_SZ + b0 + rw * 64 +
                                i * 16 + quad * 4);

#pragma unroll
      for (int i = 0; i < 4; ++i)
#pragma unroll
        for (int j = 0; j < 4; ++j) {
          f32x4 p = __builtin_amdgcn_mfma_f32_16x16x32_bf16(
              af[i][0], bfr[j][0], (f32x4){0.f, 0.f, 0.f, 0.f}, 0, 0, 0);
          p = __builtin_amdgcn_mfma_f32_16x16x32_bf16(af[i][1], bfr[j][1], p,
                                                      0, 0, 0);
#pragma unroll
          for (int r = 0; r < 4; ++r) facc[i][j][r] += sv[i][r] * p[r];
        }

      if (kt == 0) {  // bias term, once per mode
        float bbv[4];
#pragma unroll
        for (int j = 0; j < 4; ++j)
          bbv[j] = biases[(size_t)mode * U_SZ + u0 + j * 16 + lane16];
#pragma unroll
        for (int i = 0; i < 4; ++i)
#pragma unroll
          for (int j = 0; j < 4; ++j)
#pragma unroll
            for (int r = 0; r < 4; ++r) facc[i][j][r] += sv[i][r] * bbv[j];
      }
    }
  }

  // epilogue: 4-way mode-quarter combine through one LDS buffer per rw.
  // stages: q3 writes -> q2 adds -> q1 adds -> q0 adds + stores.
  __syncthreads();
  if (q == 3) {
#pragma unroll
    for (int i = 0; i < 4; ++i)
#pragma unroll
      for (int r = 0; r < 4; ++r)
#pragma unroll
        for (int j = 0; j < 4; ++j)
          sRed[rw][i * 16 + quad * 4 + r][j * 16 + lane16] = facc[i][j][r];
  }
  __syncthreads();
  if (q == 2) {
#pragma unroll
    for (int i = 0; i < 4; ++i)
#pragma unroll
      for (int r = 0; r < 4; ++r)
#pragma unroll
        for (int j = 0; j < 4; ++j)
          sRed[rw][i * 16 + quad * 4 + r][j * 16 + lane16] += facc[i][j][r];
  }
  __syncthreads();
  if (q == 1) {
#pragma unroll
    for (int i = 0; i < 4; ++i)
#pragma unroll
      for (int r = 0; r < 4; ++r)
#pragma unroll
        for (int j = 0; j < 4; ++j)
          sRed[rw][i * 16 + quad * 4 + r][j * 16 + lane16] += facc[i][j][r];
  }
  __syncthreads();
  if (q == 0) {
#pragma unroll
    for (int i = 0; i < 4; ++i)
#pragma unroll
      for (int r = 0; r < 4; ++r) {
        int row = b0 + rw * 64 + i * 16 + quad * 4 + r;
        float* orow = out + (size_t)row * U_SZ + u0;
#pragma unroll
        for (int j = 0; j < 4; ++j)
          orow[j * 16 + lane16] =
              (facc[i][j][r] +
               sRed[rw][i * 16 + quad * 4 + r][j * 16 + lane16]) *
              0.0625f;
      }
  }
}

extern "C" void kernel_launch(void* const* d_in, const int* in_sizes, int n_in,
                              void* d_out, int out_size, void* d_ws, size_t ws_size,
                              hipStream_t stream) {
  const float* x = (const float*)d_in[0];
  const float* key_kernel = (const float*)d_in[1];
  const float* key_bias = (const float*)d_in[2];
  const float* keys_map = (const float*)d_in[3];
  const float* kernels = (const float*)d_in[4];
  const float* biases = (const float*)d_in[5];
  float* out = (float*)d_out;

  // ws: xbf 8MB | kbf 8MB | wkbf 64KB | simT 512KB
  char* p = (char*)d_ws;
  unsigned short* xbf = (unsigned short*)p;  p += (size_t)B_SZ * D_SZ * 2;
  unsigned short* kbf = (unsigned short*)p;  p += (size_t)M_SZ * U_SZ * D_SZ * 2;
  unsigned short* wkbf = (unsigned short*)p; p += (size_t)K_SZ * D_SZ * 2;
  float* simT = (float*)p;

  prep1<<<dim3(2568), 256, 0, stream>>>(x, key_kernel, kernels, xbf, kbf, wkbf);
  prep2<<<dim3(128), 256, 0, stream>>>(xbf, wkbf, key_bias, keys_map, simT);
  poly_gemm<<<dim3(512), 512, 0, stream>>>(xbf, kbf, simT, biases, out);
}

// Round 3
// 174.765 us; speedup vs baseline: 2.9767x; 2.9767x over previous
//
#include <hip/hip_runtime.h>
#include <hip/hip_bf16.h>
#include <stdint.h>

#define B_SZ 8192
#define D_SZ 512
#define U_SZ 512
#define M_SZ 16
#define K_SZ 64

typedef short bf16x8 __attribute__((ext_vector_type(8)));
typedef float f32x4 __attribute__((ext_vector_type(4)));

__device__ __forceinline__ unsigned short f2bf(float f) {
  union { float f; unsigned u; } v; v.f = f;
  unsigned r = v.u + 0x7fffu + ((v.u >> 16) & 1u);
  return (unsigned short)(r >> 16);
}

// =====================================================================
// prep1: role-split single launch. ALL outputs are fragment-linear bf16.
//  [0,2048):    kernels [M][D][U] f32 -> kbf [m][ut][kt][j][h][lane][8]
//  [2048,2056): key_kernel [D][K]     -> wkbf [kt][j][h][lane][8]
//  [2056,2568): x [B][D]              -> xbf [bt][kt][i][h][lane][8]
// lane = quad*16+lane16; elem e = k offset kt*64 + h*32 + quad*8 + e.
// =====================================================================
__global__ __launch_bounds__(256) void prep1(
    const float* __restrict__ x, const float* __restrict__ key_kernel,
    const float* __restrict__ kernels, unsigned short* __restrict__ xbf,
    unsigned short* __restrict__ kbf, unsigned short* __restrict__ wkbf) {
  __shared__ float tf[32][65];
  int bid = blockIdx.x;
  int t = threadIdx.x;

  if (bid < 2048) {
    // ---- role T: kernels -> kbf (frag-linear B operand) ----
    int m = bid >> 7;
    int rem = bid & 127;
    int a = (rem >> 3) & 15;  // d-tile (32 d's)
    int ut = rem & 7;         // u-tile (64 u's)
    int d0 = a * 32, u0 = ut * 64;
    {
      int dr = t >> 4, uc = t & 15;
      const float* src = kernels + ((size_t)m * D_SZ + d0 + dr) * U_SZ + u0 + uc * 4;
      float4 aa = *(const float4*)src;
      float4 bb = *(const float4*)(src + (size_t)16 * U_SZ);
      tf[dr][uc * 4 + 0] = aa.x; tf[dr][uc * 4 + 1] = aa.y;
      tf[dr][uc * 4 + 2] = aa.z; tf[dr][uc * 4 + 3] = aa.w;
      tf[dr + 16][uc * 4 + 0] = bb.x; tf[dr + 16][uc * 4 + 1] = bb.y;
      tf[dr + 16][uc * 4 + 2] = bb.z; tf[dr + 16][uc * 4 + 3] = bb.w;
    }
    __syncthreads();
    {
      int ur = t >> 2, dc = t & 3;  // u-row 0..63, d-oct 0..3
      int j = ur >> 4, lane16 = ur & 15;
      int kt = a >> 1, h = a & 1;   // quad == dc (d0 multiple of 32)
      unsigned short* dst = kbf +
          (((((size_t)m * 8 + ut) * 8 + kt) * 4 + j) * 2 + h) * 512 +
          ((size_t)dc * 16 + lane16) * 8;
      ushort4 lo, hi;
      lo.x = f2bf(tf[dc * 8 + 0][ur]); lo.y = f2bf(tf[dc * 8 + 1][ur]);
      lo.z = f2bf(tf[dc * 8 + 2][ur]); lo.w = f2bf(tf[dc * 8 + 3][ur]);
      hi.x = f2bf(tf[dc * 8 + 4][ur]); hi.y = f2bf(tf[dc * 8 + 5][ur]);
      hi.z = f2bf(tf[dc * 8 + 6][ur]); hi.w = f2bf(tf[dc * 8 + 7][ur]);
      *(ushort4*)dst = lo;
      *(ushort4*)(dst + 4) = hi;
    }
    return;
  }

  if (bid < 2056) {
    // ---- role W: key_kernel -> wkbf ----
    int kt = bid - 2048;
#pragma unroll
    for (int rep = 0; rep < 2; ++rep) {
      int c = rep * 256 + t;
      int j = c >> 7, h = (c >> 6) & 1, quad = (c >> 4) & 3, ln = c & 15;
      int dd = kt * 64 + h * 32 + quad * 8;
      int u = j * 16 + ln;
      unsigned short v[8];
#pragma unroll
      for (int e = 0; e < 8; ++e)
        v[e] = f2bf(key_kernel[(size_t)(dd + e) * K_SZ + u]);
      unsigned short* dst =
          wkbf + ((size_t)((kt * 4 + j) * 2 + h) * 64 + quad * 16 + ln) * 8;
#pragma unroll
      for (int e = 0; e < 8; ++e) dst[e] = v[e];
    }
    return;
  }

  // ---- role X: x -> xbf (frag-linear A operand) ----
  int xb0 = bid - 2056;
  int bt = xb0 >> 3, i = xb0 & 7;
  int b0 = xb0 * 16;
#pragma unroll
  for (int rep = 0; rep < 4; ++rep) {
    int idx = rep * 256 + t;
    int kt = idx >> 7, h = (idx >> 6) & 1, quad = (idx >> 4) & 3, ln = idx & 15;
    const float* src = x + (size_t)(b0 + ln) * D_SZ + kt * 64 + h * 32 + quad * 8;
    float4 a = *(const float4*)src;
    float4 b = *(const float4*)(src + 4);
    ushort4 lo, hi;
    lo.x = f2bf(a.x); lo.y = f2bf(a.y); lo.z = f2bf(a.z); lo.w = f2bf(a.w);
    hi.x = f2bf(b.x); hi.y = f2bf(b.y); hi.z = f2bf(b.z); hi.w = f2bf(b.w);
    unsigned short* dst =
        xbf + ((((size_t)bt * 8 + kt) * 8 + i) * 2 + h) * 512 +
        ((size_t)quad * 16 + ln) * 8;
    *(ushort4*)dst = lo;
    *(ushort4*)(dst + 4) = hi;
  }
}

// =====================================================================
// prep2: keyv = xb @ Wk + bias (MFMA, frags direct from global), then sim.
// 128 blocks x 64 rows. No LDS in GEMM loop; one barrier before sim phase.
// =====================================================================
__global__ __launch_bounds__(256) void prep2(
    const unsigned short* __restrict__ xbf, const unsigned short* __restrict__ wkbf,
    const float* __restrict__ key_bias, const float* __restrict__ keys_map,
    float* __restrict__ simT) {
  __shared__ float kv[64][68];
  __shared__ float sKM[16][64];
  int t = threadIdx.x, w = t >> 6, l = t & 63;
  int blk = blockIdx.x;
  int b0 = blk * 64, bt = blk >> 1, ibase = (blk & 1) * 4;
  int lane16 = l & 15, quad = l >> 4;

  ((float4*)sKM)[t] = ((const float4*)keys_map)[t];

  f32x4 acc[4];
#pragma unroll
  for (int j = 0; j < 4; ++j) acc[j] = (f32x4){0.f, 0.f, 0.f, 0.f};

  for (int kt = 0; kt < 8; ++kt) {
    bf16x8 af[2];
#pragma unroll
    for (int h = 0; h < 2; ++h)
      af[h] = *(const bf16x8*)(xbf +
                               ((((size_t)bt * 8 + kt) * 8 + ibase + w) * 2 + h) * 512 +
                               (size_t)l * 8);
#pragma unroll
    for (int j = 0; j < 4; ++j) {
      bf16x8 b0f = *(const bf16x8*)(wkbf + ((size_t)((kt * 4 + j) * 2 + 0) * 64 + l) * 8);
      bf16x8 b1f = *(const bf16x8*)(wkbf + ((size_t)((kt * 4 + j) * 2 + 1) * 64 + l) * 8);
      acc[j] = __builtin_amdgcn_mfma_f32_16x16x32_bf16(af[0], b0f, acc[j], 0, 0, 0);
      acc[j] = __builtin_amdgcn_mfma_f32_16x16x32_bf16(af[1], b1f, acc[j], 0, 0, 0);
    }
  }
#pragma unroll
  for (int j = 0; j < 4; ++j) {
    float bc = key_bias[j * 16 + lane16];
#pragma unroll
    for (int r = 0; r < 4; ++r)
      kv[w * 16 + quad * 4 + r][j * 16 + lane16] = acc[j][r] + bc;
  }
  __syncthreads();

  int row = t >> 2, mg = (t & 3) * 4;
  float d2[4] = {0.f, 0.f, 0.f, 0.f};
#pragma unroll 8
  for (int k = 0; k < 64; ++k) {
    float kvv = kv[row][k];
#pragma unroll
    for (int q = 0; q < 4; ++q) {
      float df = kvv - sKM[mg + q][k];
      d2[q] += df * df;
    }
  }
#pragma unroll
  for (int q = 0; q < 4; ++q)
    simT[(size_t)(mg + q) * B_SZ + b0 + row] = 1.0f / (sqrtf(d2[q]) + 1.0f);
}

// =====================================================================
// poly_gemm: out[b,u] = (1/16) sum_m sim[b,m]*(x@kernels_m + biases_m)
// ROUND-2 (resubmit; round-2 bench was an infra failure, kernel never ran):
// back to the proven 256-thread / 4-wave structure (round-1's 512-thread
// block triggered the launch-bounds VGPR squeeze to 64 regs -> 1.9GB of
// scratch spill). Occupancy raised via GRID instead:
// 1024 blocks = 64 bt (128 rows) x 16 utile (32 cols). 4 blocks/CU =
// 16 waves/CU = 4 waves/SIMD (round-0 was grid-limited to 2 blocks/CU).
// facc halves to [4][2] (32 VGPR) -> natural pressure ~90-110 < 128.
// XCD pinning: utile = (bid&7)*2 + ((bid>>3)&1); both 32-wide subtiles
// of one 64-wide kbf slice (1MB) stay in one XCD's L2; kbf L2 traffic
// unchanged vs round-0 (rows/block still 128).
// MAIN LOOP HAS NO LDS AND NO BARRIERS; LDS only for the 2-barrier
// epilogue mode-half combine (18KB).
// =====================================================================
__global__ __launch_bounds__(256, 2) void poly_gemm(
    const unsigned short* __restrict__ xbf,  // A frag-linear
    const unsigned short* __restrict__ kbf,  // B frag-linear
    const float* __restrict__ simT,          // [M][B]
    const float* __restrict__ biases,        // [M][U] f32
    float* __restrict__ out) {               // [B][U]
  __shared__ float sRed[2][64][36];  // 18 KB, epilogue only

  int t = threadIdx.x, w = t >> 6, l = t & 63;
  int bid = blockIdx.x;
  int xcd = bid & 7;
  int sub = (bid >> 3) & 1;
  int bt = bid >> 4;                 // 0..63 (128-row tiles)
  int utile = xcd * 2 + sub;         // 0..15 (32-col tiles)
  int ut_kbf = utile >> 1;           // 0..7 (64-col kbf slices)
  int j_off = (utile & 1) * 2;       // 0 or 2
  int b0 = bt * 128, u0 = utile * 32;
  int half = w >> 1, rw = w & 1;
  int lane16 = l & 15, quad = l >> 4;

  f32x4 facc[4][2];
#pragma unroll
  for (int i = 0; i < 4; ++i)
#pragma unroll
    for (int j = 0; j < 2; ++j) facc[i][j] = (f32x4){0.f, 0.f, 0.f, 0.f};

#pragma unroll 1
  for (int kt = 0; kt < 8; ++kt) {
    bf16x8 af[4][2];
#pragma unroll
    for (int ii = 0; ii < 4; ++ii)
#pragma unroll
      for (int h = 0; h < 2; ++h)
        af[ii][h] = *(const bf16x8*)(
            xbf + ((((size_t)bt * 8 + kt) * 8 + rw * 4 + ii) * 2 + h) * 512 +
            (size_t)l * 8);

#pragma unroll 2
    for (int mi = 0; mi < 8; ++mi) {
      int mode = half * 8 + mi;
      const unsigned short* bb =
          kbf + ((((size_t)mode * 8 + ut_kbf) * 8 + kt) * 4) * 2 * 512;
      bf16x8 bfr[2][2];
#pragma unroll
      for (int j = 0; j < 2; ++j)
#pragma unroll
        for (int h = 0; h < 2; ++h)
          bfr[j][h] = *(const bf16x8*)(bb + ((size_t)((j_off + j) * 2 + h)) * 512 +
                                       (size_t)l * 8);

      f32x4 sv[4];
#pragma unroll
      for (int i = 0; i < 4; ++i)
        sv[i] = *(const f32x4*)(simT + (size_t)mode * B_SZ + b0 + rw * 64 +
                                i * 16 + quad * 4);

#pragma unroll
      for (int i = 0; i < 4; ++i)
#pragma unroll
        for (int j = 0; j < 2; ++j) {
          f32x4 p = __builtin_amdgcn_mfma_f32_16x16x32_bf16(
              af[i][0], bfr[j][0], (f32x4){0.f, 0.f, 0.f, 0.f}, 0, 0, 0);
          p = __builtin_amdgcn_mfma_f32_16x16x32_bf16(af[i][1], bfr[j][1], p,
                                                      0, 0, 0);
#pragma unroll
          for (int r = 0; r < 4; ++r) facc[i][j][r] += sv[i][r] * p[r];
        }

      if (kt == 0) {  // bias term, once per mode
        float bbv[2];
#pragma unroll
        for (int j = 0; j < 2; ++j)
          bbv[j] = biases[(size_t)mode * U_SZ + u0 + j * 16 + lane16];
#pragma unroll
        for (int i = 0; i < 4; ++i)
#pragma unroll
          for (int j = 0; j < 2; ++j)
#pragma unroll
            for (int r = 0; r < 4; ++r) facc[i][j][r] += sv[i][r] * bbv[j];
      }
    }
  }

  // epilogue: combine mode-halves via LDS (the only barriers in the kernel)
  __syncthreads();
  if (half == 1) {
#pragma unroll
    for (int i = 0; i < 4; ++i)
#pragma unroll
      for (int r = 0; r < 4; ++r)
#pragma unroll
        for (int j = 0; j < 2; ++j)
          sRed[rw][i * 16 + quad * 4 + r][j * 16 + lane16] = facc[i][j][r];
  }
  __syncthreads();
  if (half == 0) {
#pragma unroll
    for (int i = 0; i < 4; ++i)
#pragma unroll
      for (int r = 0; r < 4; ++r) {
        int row = b0 + rw * 64 + i * 16 + quad * 4 + r;
        float* orow = out + (size_t)row * U_SZ + u0;
#pragma unroll
        for (int j = 0; j < 2; ++j)
          orow[j * 16 + lane16] =
              (facc[i][j][r] +
               sRed[rw][i * 16 + quad * 4 + r][j * 16 + lane16]) *
              0.0625f;
      }
  }
}

extern "C" void kernel_launch(void* const* d_in, const int* in_sizes, int n_in,
                              void* d_out, int out_size, void* d_ws, size_t ws_size,
                              hipStream_t stream) {
  const float* x = (const float*)d_in[0];
  const float* key_kernel = (const float*)d_in[1];
  const float* key_bias = (const float*)d_in[2];
  const float* keys_map = (const float*)d_in[3];
  const float* kernels = (const float*)d_in[4];
  const float* biases = (const float*)d_in[5];
  float* out = (float*)d_out;

  // ws: xbf 8MB | kbf 8MB | wkbf 64KB | simT 512KB
  char* p = (char*)d_ws;
  unsigned short* xbf = (unsigned short*)p;  p += (size_t)B_SZ * D_SZ * 2;
  unsigned short* kbf = (unsigned short*)p;  p += (size_t)M_SZ * U_SZ * D_SZ * 2;
  unsigned short* wkbf = (unsigned short*)p; p += (size_t)K_SZ * D_SZ * 2;
  float* simT = (float*)p;

  prep1<<<dim3(2568), 256, 0, stream>>>(x, key_kernel, kernels, xbf, kbf, wkbf);
  prep2<<<dim3(128), 256, 0, stream>>>(xbf, wkbf, key_bias, keys_map, simT);
  poly_gemm<<<dim3(1024), 256, 0, stream>>>(xbf, kbf, simT, biases, out);
}

// Round 4
// 172.744 us; speedup vs baseline: 3.0115x; 1.0117x over previous
//
#include <hip/hip_runtime.h>
#include <hip/hip_bf16.h>
#include <stdint.h>

#define B_SZ 8192
#define D_SZ 512
#define U_SZ 512
#define M_SZ 16
#define K_SZ 64

typedef short bf16x8 __attribute__((ext_vector_type(8)));
typedef float f32x4 __attribute__((ext_vector_type(4)));

__device__ __forceinline__ unsigned short f2bf(float f) {
  union { float f; unsigned u; } v; v.f = f;
  unsigned r = v.u + 0x7fffu + ((v.u >> 16) & 1u);
  return (unsigned short)(r >> 16);
}

// =====================================================================
// prep1: role-split single launch. ALL outputs are fragment-linear bf16.
//  [0,2048):    kernels [M][D][U] f32 -> kbf [m][ut][kt][j][h][lane][8]
//  [2048,2056): key_kernel [D][K]     -> wkbf [kt][j][h][lane][8]
//  [2056,2568): x [B][D]              -> xbf [bt][kt][i][h][lane][8]
// lane = quad*16+lane16; elem e = k offset kt*64 + h*32 + quad*8 + e.
// =====================================================================
__global__ __launch_bounds__(256) void prep1(
    const float* __restrict__ x, const float* __restrict__ key_kernel,
    const float* __restrict__ kernels, unsigned short* __restrict__ xbf,
    unsigned short* __restrict__ kbf, unsigned short* __restrict__ wkbf) {
  __shared__ float tf[32][65];
  int bid = blockIdx.x;
  int t = threadIdx.x;

  if (bid < 2048) {
    // ---- role T: kernels -> kbf (frag-linear B operand) ----
    int m = bid >> 7;
    int rem = bid & 127;
    int a = (rem >> 3) & 15;  // d-tile (32 d's)
    int ut = rem & 7;         // u-tile (64 u's)
    int d0 = a * 32, u0 = ut * 64;
    {
      int dr = t >> 4, uc = t & 15;
      const float* src = kernels + ((size_t)m * D_SZ + d0 + dr) * U_SZ + u0 + uc * 4;
      float4 aa = *(const float4*)src;
      float4 bb = *(const float4*)(src + (size_t)16 * U_SZ);
      tf[dr][uc * 4 + 0] = aa.x; tf[dr][uc * 4 + 1] = aa.y;
      tf[dr][uc * 4 + 2] = aa.z; tf[dr][uc * 4 + 3] = aa.w;
      tf[dr + 16][uc * 4 + 0] = bb.x; tf[dr + 16][uc * 4 + 1] = bb.y;
      tf[dr + 16][uc * 4 + 2] = bb.z; tf[dr + 16][uc * 4 + 3] = bb.w;
    }
    __syncthreads();
    {
      int ur = t >> 2, dc = t & 3;  // u-row 0..63, d-oct 0..3
      int j = ur >> 4, lane16 = ur & 15;
      int kt = a >> 1, h = a & 1;   // quad == dc (d0 multiple of 32)
      unsigned short* dst = kbf +
          (((((size_t)m * 8 + ut) * 8 + kt) * 4 + j) * 2 + h) * 512 +
          ((size_t)dc * 16 + lane16) * 8;
      ushort4 lo, hi;
      lo.x = f2bf(tf[dc * 8 + 0][ur]); lo.y = f2bf(tf[dc * 8 + 1][ur]);
      lo.z = f2bf(tf[dc * 8 + 2][ur]); lo.w = f2bf(tf[dc * 8 + 3][ur]);
      hi.x = f2bf(tf[dc * 8 + 4][ur]); hi.y = f2bf(tf[dc * 8 + 5][ur]);
      hi.z = f2bf(tf[dc * 8 + 6][ur]); hi.w = f2bf(tf[dc * 8 + 7][ur]);
      *(ushort4*)dst = lo;
      *(ushort4*)(dst + 4) = hi;
    }
    return;
  }

  if (bid < 2056) {
    // ---- role W: key_kernel -> wkbf ----
    int kt = bid - 2048;
#pragma unroll
    for (int rep = 0; rep < 2; ++rep) {
      int c = rep * 256 + t;
      int j = c >> 7, h = (c >> 6) & 1, quad = (c >> 4) & 3, ln = c & 15;
      int dd = kt * 64 + h * 32 + quad * 8;
      int u = j * 16 + ln;
      unsigned short v[8];
#pragma unroll
      for (int e = 0; e < 8; ++e)
        v[e] = f2bf(key_kernel[(size_t)(dd + e) * K_SZ + u]);
      unsigned short* dst =
          wkbf + ((size_t)((kt * 4 + j) * 2 + h) * 64 + quad * 16 + ln) * 8;
#pragma unroll
      for (int e = 0; e < 8; ++e) dst[e] = v[e];
    }
    return;
  }

  // ---- role X: x -> xbf (frag-linear A operand) ----
  int xb0 = bid - 2056;
  int bt = xb0 >> 3, i = xb0 & 7;
  int b0 = xb0 * 16;
#pragma unroll
  for (int rep = 0; rep < 4; ++rep) {
    int idx = rep * 256 + t;
    int kt = idx >> 7, h = (idx >> 6) & 1, quad = (idx >> 4) & 3, ln = idx & 15;
    const float* src = x + (size_t)(b0 + ln) * D_SZ + kt * 64 + h * 32 + quad * 8;
    float4 a = *(const float4*)src;
    float4 b = *(const float4*)(src + 4);
    ushort4 lo, hi;
    lo.x = f2bf(a.x); lo.y = f2bf(a.y); lo.z = f2bf(a.z); lo.w = f2bf(a.w);
    hi.x = f2bf(b.x); hi.y = f2bf(b.y); hi.z = f2bf(b.z); hi.w = f2bf(b.w);
    unsigned short* dst =
        xbf + ((((size_t)bt * 8 + kt) * 8 + i) * 2 + h) * 512 +
        ((size_t)quad * 16 + ln) * 8;
    *(ushort4*)dst = lo;
    *(ushort4*)(dst + 4) = hi;
  }
}

// =====================================================================
// prep2: keyv = xb @ Wk + bias (MFMA, frags direct from global), then sim.
// 128 blocks x 64 rows. No LDS in GEMM loop; one barrier before sim phase.
// =====================================================================
__global__ __launch_bounds__(256) void prep2(
    const unsigned short* __restrict__ xbf, const unsigned short* __restrict__ wkbf,
    const float* __restrict__ key_bias, const float* __restrict__ keys_map,
    float* __restrict__ simT) {
  __shared__ float kv[64][68];
  __shared__ float sKM[16][64];
  int t = threadIdx.x, w = t >> 6, l = t & 63;
  int blk = blockIdx.x;
  int b0 = blk * 64, bt = blk >> 1, ibase = (blk & 1) * 4;
  int lane16 = l & 15, quad = l >> 4;

  ((float4*)sKM)[t] = ((const float4*)keys_map)[t];

  f32x4 acc[4];
#pragma unroll
  for (int j = 0; j < 4; ++j) acc[j] = (f32x4){0.f, 0.f, 0.f, 0.f};

  for (int kt = 0; kt < 8; ++kt) {
    bf16x8 af[2];
#pragma unroll
    for (int h = 0; h < 2; ++h)
      af[h] = *(const bf16x8*)(xbf +
                               ((((size_t)bt * 8 + kt) * 8 + ibase + w) * 2 + h) * 512 +
                               (size_t)l * 8);
#pragma unroll
    for (int j = 0; j < 4; ++j) {
      bf16x8 b0f = *(const bf16x8*)(wkbf + ((size_t)((kt * 4 + j) * 2 + 0) * 64 + l) * 8);
      bf16x8 b1f = *(const bf16x8*)(wkbf + ((size_t)((kt * 4 + j) * 2 + 1) * 64 + l) * 8);
      acc[j] = __builtin_amdgcn_mfma_f32_16x16x32_bf16(af[0], b0f, acc[j], 0, 0, 0);
      acc[j] = __builtin_amdgcn_mfma_f32_16x16x32_bf16(af[1], b1f, acc[j], 0, 0, 0);
    }
  }
#pragma unroll
  for (int j = 0; j < 4; ++j) {
    float bc = key_bias[j * 16 + lane16];
#pragma unroll
    for (int r = 0; r < 4; ++r)
      kv[w * 16 + quad * 4 + r][j * 16 + lane16] = acc[j][r] + bc;
  }
  __syncthreads();

  int row = t >> 2, mg = (t & 3) * 4;
  float d2[4] = {0.f, 0.f, 0.f, 0.f};
#pragma unroll 8
  for (int k = 0; k < 64; ++k) {
    float kvv = kv[row][k];
#pragma unroll
    for (int q = 0; q < 4; ++q) {
      float df = kvv - sKM[mg + q][k];
      d2[q] += df * df;
    }
  }
#pragma unroll
  for (int q = 0; q < 4; ++q)
    simT[(size_t)(mg + q) * B_SZ + b0 + row] = 1.0f / (sqrtf(d2[q]) + 1.0f);
}

// =====================================================================
// poly_gemm v5: out[b,u] = (1/16) sum_m sim[b,m]*(x@kernels_m + biases_m)
//
// ROUND-4 theory: rounds 0/3 proved the limiter is the VMEM fragment-
// delivery pipe (~37 B/cy/CU effective): occupancy 2x'd with ZERO time
// change, MfmaUtil pinned ~32%. Fix: move B-fragment + sim + bias
// delivery to the LDS pipe (separate ~112 B/cy).
//  - geometry: 512 blocks (64 bt x 8 ut, ut=bid&7 XCD-pinned), 256 thr,
//    4 waves = rw(row 64-half) x half(mode 8-half); wave tile 64x64.
//  - each wave PRIVATELY double-buffers its (kt,mode) 8KB kbf slice in
//    LDS via global_load_lds (wave-uniform dest, 8x 1KB chunks), one
//    iteration ahead. NO BARRIERS in the main loop; waves self-sync via
//    counted s_waitcnt vmcnt(8) (vmcnt(16) at mi==0 to let the af loads
//    ride in the window). Never vmcnt(0) in-loop (T4).
//  - sim (8KB) and biases (4KB) staged to LDS once at block start;
//    sv/bias reads are 16-lane broadcasts (conflict-free).
//  - only in-loop VMEM: 8 global_load_lds per iter + 8 af loads per kt.
//  - LDS 76KB -> exactly 2 blocks/CU x 512 blocks = full residency.
//  - epilogue: mode-half combine via sRed overlaid on kbuf (after
//    vmcnt(0)+syncthreads).
// =====================================================================
__device__ __forceinline__ void stage_slice(const unsigned short* src,
                                            unsigned short* dst_lds) {
#pragma unroll
  for (int c = 0; c < 8; ++c)
    __builtin_amdgcn_global_load_lds(
        (const __attribute__((address_space(1))) unsigned int*)(src + c * 512),
        (__attribute__((address_space(3))) unsigned int*)(dst_lds + c * 512),
        16, 0, 0);
}

__global__ __launch_bounds__(256) void poly_gemm(
    const unsigned short* __restrict__ xbf,  // A frag-linear
    const unsigned short* __restrict__ kbf,  // B frag-linear
    const float* __restrict__ simT,          // [M][B]
    const float* __restrict__ biases,        // [M][U] f32
    float* __restrict__ out) {               // [B][U]
  // smem map: [0,64K): 4 x per-wave 16KB kbuf (2 x 8KB dbuf)
  //           [64K,72K): sSim [16][128] f32
  //           [72K,76K): sBias [16][64] f32
  // epilogue overlays sRed (2x64x68 f32 = 34.8KB) on the kbuf region.
  __shared__ __align__(16) char smem[77824];

  int t = threadIdx.x, w = t >> 6, l = t & 63;
  int bid = blockIdx.x;
  int ut = bid & 7, bt = bid >> 3;
  int b0 = bt * 128, u0 = ut * 64;
  int half = w >> 1, rw = w & 1;
  int lane16 = l & 15, quad = l >> 4;

  float* sSim = (float*)(smem + 65536);
  float* sBias = (float*)(smem + 73728);
  unsigned short* kbuf = (unsigned short*)(smem + w * 16384);

  // ---- stage sim [16][128] and bias [16][64] (once) ----
  {
    int m = t >> 4, c = (t & 15) * 8;
    const float* src = simT + (size_t)m * B_SZ + b0 + c;
    float4 a = *(const float4*)src;
    float4 b = *(const float4*)(src + 4);
    float4* dst = (float4*)(sSim + m * 128 + c);
    dst[0] = a; dst[1] = b;
    int cb = (t & 15) * 4;
    *(float4*)(sBias + m * 64 + cb) =
        *(const float4*)(biases + (size_t)m * U_SZ + u0 + cb);
  }
  __syncthreads();

  f32x4 facc[4][4];
#pragma unroll
  for (int i = 0; i < 4; ++i)
#pragma unroll
    for (int j = 0; j < 4; ++j) facc[i][j] = (f32x4){0.f, 0.f, 0.f, 0.f};

  // kbf slice index for (mode, kt): ((mode*8 + ut)*8 + kt) * 4096 shorts
  const unsigned short* kbf_l = kbf + (size_t)l * 8;  // lane offset baked in

  // prologue: stage (mode=half*8, kt=0) into buf 0
  stage_slice(kbf_l + ((((size_t)(half * 8) * 8 + ut) * 8) + 0) * 4096, kbuf);

#pragma unroll 1
  for (int kt = 0; kt < 8; ++kt) {
    bf16x8 af[4][2];
#pragma unroll
    for (int ii = 0; ii < 4; ++ii)
#pragma unroll
      for (int h = 0; h < 2; ++h)
        af[ii][h] = *(const bf16x8*)(
            xbf + ((((size_t)bt * 8 + kt) * 8 + rw * 4 + ii) * 2 + h) * 512 +
            (size_t)l * 8);

#pragma unroll
    for (int mi = 0; mi < 8; ++mi) {
      int mode = half * 8 + mi;
      // stage next slice (wraps to (mode0,kt0) at the very end; harmless)
      {
        int nmi = (mi + 1) & 7;
        int nkt = (mi == 7) ? ((kt + 1) & 7) : kt;
        stage_slice(
            kbf_l + ((((size_t)(half * 8 + nmi) * 8 + ut) * 8) + nkt) * 4096,
            kbuf + ((mi + 1) & 1) * 4096);
      }
      // wait for current buffer (8 newest = next-stage; at mi==0 also
      // allow the 8 af loads in the window)
      if (mi == 0)
        asm volatile("s_waitcnt vmcnt(16)" ::: "memory");
      else
        asm volatile("s_waitcnt vmcnt(8)" ::: "memory");

      const unsigned short* lb = kbuf + (mi & 1) * 4096;
      bf16x8 bfr[4][2];
#pragma unroll
      for (int j = 0; j < 4; ++j)
#pragma unroll
        for (int h = 0; h < 2; ++h)
          bfr[j][h] = *(const bf16x8*)(lb + (j * 2 + h) * 512 + (size_t)l * 8);

      f32x4 sv[4];
#pragma unroll
      for (int i = 0; i < 4; ++i)
        sv[i] = *(const f32x4*)(sSim + mode * 128 + rw * 64 + i * 16 + quad * 4);

#pragma unroll
      for (int i = 0; i < 4; ++i)
#pragma unroll
        for (int j = 0; j < 4; ++j) {
          f32x4 p = __builtin_amdgcn_mfma_f32_16x16x32_bf16(
              af[i][0], bfr[j][0], (f32x4){0.f, 0.f, 0.f, 0.f}, 0, 0, 0);
          p = __builtin_amdgcn_mfma_f32_16x16x32_bf16(af[i][1], bfr[j][1], p,
                                                      0, 0, 0);
#pragma unroll
          for (int r = 0; r < 4; ++r) facc[i][j][r] += sv[i][r] * p[r];
        }

      if (kt == 0) {  // bias term, once per mode (from LDS — no VMEM)
        float bbv[4];
#pragma unroll
        for (int j = 0; j < 4; ++j)
          bbv[j] = sBias[mode * 64 + j * 16 + lane16];
#pragma unroll
        for (int i = 0; i < 4; ++i)
#pragma unroll
          for (int j = 0; j < 4; ++j)
#pragma unroll
            for (int r = 0; r < 4; ++r) facc[i][j][r] += sv[i][r] * bbv[j];
      }
    }
  }

  // drain the wrap-stage DMA before overlaying sRed on kbuf
  asm volatile("s_waitcnt vmcnt(0)" ::: "memory");
  __syncthreads();

  float* sRed = (float*)smem;  // [2][64][68]
  if (half == 1) {
#pragma unroll
    for (int i = 0; i < 4; ++i)
#pragma unroll
      for (int r = 0; r < 4; ++r)
#pragma unroll
        for (int j = 0; j < 4; ++j)
          sRed[(rw * 64 + i * 16 + quad * 4 + r) * 68 + j * 16 + lane16] =
              facc[i][j][r];
  }
  __syncthreads();
  if (half == 0) {
#pragma unroll
    for (int i = 0; i < 4; ++i)
#pragma unroll
      for (int r = 0; r < 4; ++r) {
        int row = b0 + rw * 64 + i * 16 + quad * 4 + r;
        float* orow = out + (size_t)row * U_SZ + u0;
#pragma unroll
        for (int j = 0; j < 4; ++j)
          orow[j * 16 + lane16] =
              (facc[i][j][r] +
               sRed[(rw * 64 + i * 16 + quad * 4 + r) * 68 + j * 16 + lane16]) *
              0.0625f;
      }
  }
}

extern "C" void kernel_launch(void* const* d_in, const int* in_sizes, int n_in,
                              void* d_out, int out_size, void* d_ws, size_t ws_size,
                              hipStream_t stream) {
  const float* x = (const float*)d_in[0];
  const float* key_kernel = (const float*)d_in[1];
  const float* key_bias = (const float*)d_in[2];
  const float* keys_map = (const float*)d_in[3];
  const float* kernels = (const float*)d_in[4];
  const float* biases = (const float*)d_in[5];
  float* out = (float*)d_out;

  // ws: xbf 8MB | kbf 8MB | wkbf 64KB | simT 512KB
  char* p = (char*)d_ws;
  unsigned short* xbf = (unsigned short*)p;  p += (size_t)B_SZ * D_SZ * 2;
  unsigned short* kbf = (unsigned short*)p;  p += (size_t)M_SZ * U_SZ * D_SZ * 2;
  unsigned short* wkbf = (unsigned short*)p; p += (size_t)K_SZ * D_SZ * 2;
  float* simT = (float*)p;

  prep1<<<dim3(2568), 256, 0, stream>>>(x, key_kernel, kernels, xbf, kbf, wkbf);
  prep2<<<dim3(128), 256, 0, stream>>>(xbf, wkbf, key_bias, keys_map, simT);
  poly_gemm<<<dim3(512), 256, 0, stream>>>(xbf, kbf, simT, biases, out);
}